// Round 1
// baseline (1437.644 us; speedup 1.0000x reference)
//
#include <hip/hip_runtime.h>
#include <hip/hip_bf16.h>
#include <float.h>

// Problem constants (OSG_C_29987461660961)
#define NTOK 2048
#define FDIM 1024
#define HDIM 512
#define EDIM 256
#define BATCH 2
#define KSEG 30
#define NP1 2049
static const size_t ST2 = (size_t)NP1 * NP1;   // Sp per-batch element count

// ---------------------------------------------------------------------------
// Shared NT GEMM: C[i][j] = sum_k A[i*lda+k]*B[j*ldb+k]  (+bias / relu / D-xform)
// MODE 0: bias+relu (h), MODE 1: bias (e), MODE 2: corr -> D epilogue
// Tiles: 64x64, BK=32, 256 threads, 4x4 microtile. All dims divisible (no guards).
// ---------------------------------------------------------------------------
template<int MODE>
__global__ __launch_bounds__(256)
void gemm_nt(const float* __restrict__ A, int lda, size_t strideA,
             const float* __restrict__ Bm, int ldb, size_t strideB,
             const float* __restrict__ bias,
             float* __restrict__ C, int ldc, size_t strideC,
             int K, const float* __restrict__ dvec)
{
    __shared__ float As[32][68];   // [k][m], LD=68 keeps float4 reads 16B-aligned
    __shared__ float Bs[32][68];   // [k][n]
    const int z = blockIdx.z;
    const float* Ab = A + (size_t)z * strideA;
    const float* Bb = Bm + (size_t)z * strideB;
    float* Cb = C + (size_t)z * strideC;

    const int t = threadIdx.x;
    const int tx = t & 15, ty = t >> 4;
    const int lrow = t >> 3, lkv = t & 7;
    const int by = blockIdx.y, bx = blockIdx.x;

    float acc[4][4] = {};
    const int ktiles = K >> 5;
    for (int kt = 0; kt < ktiles; ++kt) {
#pragma unroll
        for (int h = 0; h < 2; ++h) {
            const int r = lrow + h * 32;
            const float4 av = *(const float4*)(Ab + (size_t)(by * 64 + r) * lda + kt * 32 + lkv * 4);
            As[lkv * 4 + 0][r] = av.x; As[lkv * 4 + 1][r] = av.y;
            As[lkv * 4 + 2][r] = av.z; As[lkv * 4 + 3][r] = av.w;
            const float4 bv = *(const float4*)(Bb + (size_t)(bx * 64 + r) * ldb + kt * 32 + lkv * 4);
            Bs[lkv * 4 + 0][r] = bv.x; Bs[lkv * 4 + 1][r] = bv.y;
            Bs[lkv * 4 + 2][r] = bv.z; Bs[lkv * 4 + 3][r] = bv.w;
        }
        __syncthreads();
#pragma unroll
        for (int kk = 0; kk < 32; ++kk) {
            const float4 a = *(const float4*)&As[kk][ty * 4];
            const float4 b = *(const float4*)&Bs[kk][tx * 4];
            const float ar[4] = {a.x, a.y, a.z, a.w};
            const float br[4] = {b.x, b.y, b.z, b.w};
#pragma unroll
            for (int i = 0; i < 4; ++i)
#pragma unroll
                for (int j = 0; j < 4; ++j)
                    acc[i][j] = fmaf(ar[i], br[j], acc[i][j]);
        }
        __syncthreads();
    }

    const int row0 = by * 64 + ty * 4;
    const int col0 = bx * 64 + tx * 4;
    if (MODE == 2) {
        float di[4], dj[4];
#pragma unroll
        for (int i = 0; i < 4; ++i) di[i] = dvec[z * NTOK + row0 + i];
#pragma unroll
        for (int j = 0; j < 4; ++j) dj[j] = dvec[z * NTOK + col0 + j];
#pragma unroll
        for (int i = 0; i < 4; ++i) {
            float4 v;
            float o[4];
#pragma unroll
            for (int j = 0; j < 4; ++j) {
                const float den = sqrtf(fmaxf(di[i] * dj[j], 1e-8f));
                o[j] = 0.5f * (1.0f - acc[i][j] / den);
            }
            v.x = o[0]; v.y = o[1]; v.z = o[2]; v.w = o[3];
            *(float4*)(Cb + (size_t)(row0 + i) * ldc + col0) = v;
        }
    } else {
#pragma unroll
        for (int i = 0; i < 4; ++i) {
            float o[4];
#pragma unroll
            for (int j = 0; j < 4; ++j) {
                float v = acc[i][j] + bias[col0 + j];
                if (MODE == 0) v = fmaxf(v, 0.0f);
                o[j] = v;
            }
            float4 v4; v4.x = o[0]; v4.y = o[1]; v4.z = o[2]; v4.w = o[3];
            *(float4*)(Cb + (size_t)(row0 + i) * ldc + col0) = v4;
        }
    }
}

// d[row] = sum_k e[row][k]^2 ; one wave per row (256 = 64 lanes * float4)
__global__ __launch_bounds__(256)
void rownorm_kernel(const float* __restrict__ e, float* __restrict__ dvec)
{
    const int wid = (blockIdx.x * 256 + threadIdx.x) >> 6;
    const int lane = threadIdx.x & 63;
    if (wid >= BATCH * NTOK) return;
    const float4 v = *(const float4*)(e + (size_t)wid * EDIM + lane * 4);
    float s = v.x * v.x + v.y * v.y + v.z * v.z + v.w * v.w;
#pragma unroll
    for (int off = 32; off; off >>= 1) s += __shfl_xor(s, off);
    if (lane == 0) dvec[wid] = s;
}

// Row-wise inclusive scan of D (f32) into Sp rows 1..N (f64). Sp[r][0]=0.
__global__ __launch_bounds__(256)
void sat_row_kernel(const float* __restrict__ D, double* __restrict__ Sp)
{
    const int b = blockIdx.y;
    const int r = blockIdx.x + 1;  // 1..N
    const float* drow = D + (size_t)b * NTOK * NTOK + (size_t)(r - 1) * NTOK;
    double* sprow = Sp + (size_t)b * ST2 + (size_t)r * NP1;
    const int t = threadIdx.x, lane = t & 63, wv = t >> 6;
    __shared__ double wtot[4];
    double carry = 0.0;
    if (t == 0) sprow[0] = 0.0;
    for (int ch = 0; ch < NTOK / 256; ++ch) {
        double v = (double)drow[ch * 256 + t];
#pragma unroll
        for (int d = 1; d < 64; d <<= 1) {
            const double u = __shfl_up(v, (unsigned)d, 64);
            if (lane >= d) v += u;
        }
        if (lane == 63) wtot[wv] = v;
        __syncthreads();
        double pre = carry;
        for (int ww = 0; ww < wv; ++ww) pre += wtot[ww];
        const double tot = carry + wtot[0] + wtot[1] + wtot[2] + wtot[3];
        sprow[ch * 256 + t + 1] = v + pre;
        __syncthreads();
        carry = tot;
    }
}

// Column cumsum of Sp in 3 phases (strips of 256 rows) for parallelism.
__global__ void satc1(const double* __restrict__ Sp, double* __restrict__ aux)
{
    const int b = blockIdx.z, s = blockIdx.y;
    const int c = blockIdx.x * 256 + threadIdx.x;
    if (c > NTOK) return;
    const double* sp = Sp + (size_t)b * ST2;
    double tt = 0.0;
    const int r0 = s * 256 + 1;
    for (int r = r0; r < r0 + 256; ++r) tt += sp[(size_t)r * NP1 + c];
    aux[(size_t)(b * 8 + s) * NP1 + c] = tt;
}
__global__ void satc2(double* __restrict__ aux)
{
    const int b = blockIdx.y;
    const int c = blockIdx.x * 256 + threadIdx.x;
    if (c > NTOK) return;
    double run = 0.0;
    for (int s = 0; s < 8; ++s) {
        const size_t id = (size_t)(b * 8 + s) * NP1 + c;
        const double tt = aux[id]; aux[id] = run; run += tt;
    }
}
__global__ void satc3(double* __restrict__ Sp, const double* __restrict__ aux)
{
    const int b = blockIdx.z, s = blockIdx.y;
    const int c = blockIdx.x * 256 + threadIdx.x;
    if (c > NTOK) return;
    double* sp = Sp + (size_t)b * ST2;
    if (s == 0) sp[c] = 0.0;  // row 0 = zeros
    double run = aux[(size_t)(b * 8 + s) * NP1 + c];
    const int r0 = s * 256 + 1;
    for (int r = r0; r < r0 + 256; ++r) {
        const size_t id = (size_t)r * NP1 + c;
        run += sp[id];
        sp[id] = run;
    }
}

__global__ void diag_kernel(const double* __restrict__ Sp, double* __restrict__ dg)
{
    const int b = blockIdx.y;
    const int t = blockIdx.x * 256 + threadIdx.x;
    if (t <= NTOK) dg[b * NP1 + t] = Sp[(size_t)b * ST2 + (size_t)t * NP1 + t];
}

// Bsum[i][j] = diag[j+1] + diag[i] - 2*Sp[i][j+1] (f64 math -> f32), j >= i only.
// Also emits C0[i] = Bsum[i][N-1].
__global__ __launch_bounds__(256)
void bsum_kernel(const double* __restrict__ Sp, const double* __restrict__ dg,
                 float* __restrict__ Bsum, float* __restrict__ C0)
{
    const int b = blockIdx.y, i = blockIdx.x;
    const double* sprow = Sp + (size_t)b * ST2 + (size_t)i * NP1;
    const double* dgb = dg + (size_t)b * NP1;
    const double di = dgb[i];
    float* brow = Bsum + (size_t)b * NTOK * NTOK + (size_t)i * NTOK;
    for (int j = i + threadIdx.x; j < NTOK; j += 256) {
        const double v = dgb[j + 1] + di - 2.0 * sprow[j + 1];
        brow[j] = (float)v;
        if (j == NTOK - 1) C0[b * NTOK + i] = (float)v;
    }
}

// One DP step. Wave-per-row; row j-range read once into 32-reg stash (static).
// rowmin doubles as softmax max. LDS atomic column accumulation, one global
// atomic merge per block per column.
__global__ __launch_bounds__(256)
void dp_step_kernel(const float* __restrict__ Bsum, const float* __restrict__ Cprev,
                    float* __restrict__ Cnext, float* __restrict__ tsum, int kk)
{
    __shared__ float cs[NTOK];
    __shared__ float acc[NTOK];
    const int b = blockIdx.y;
    const int t = threadIdx.x, lane = t & 63, wv = t >> 6;
    const float* Cp = Cprev + b * NTOK;
    for (int j = t; j < NTOK; j += 256) {
        cs[j] = (j < NTOK - 1) ? Cp[j + 1] : 0.0f;
        acc[j] = 0.0f;
    }
    __syncthreads();
    const int jmax = NTOK - kk;
    const int w = blockIdx.x * 4 + wv;  // 0..511 per batch
    const float* Bb = Bsum + (size_t)b * NTOK * NTOK;
    float* Cn = Cnext + b * NTOK;
    const int rows[4] = { w, 1023 - w, 1024 + w, 2047 - w };  // load-balanced cover
#pragma unroll
    for (int rr = 0; rr < 4; ++rr) {
        const int i = rows[rr];
        if (i >= jmax) { if (lane == 0) Cn[i] = 0.0f; continue; }
        const float* brow = Bb + (size_t)i * NTOK;
        const int j0 = i + lane;
        float mv[32];
        float mn = FLT_MAX;
#pragma unroll
        for (int c = 0; c < 32; ++c) {
            const int j = j0 + c * 64;
            float v = FLT_MAX;
            if (j < jmax) v = brow[j] + cs[j];
            mv[c] = v;
            mn = fminf(mn, v);
        }
#pragma unroll
        for (int off = 32; off; off >>= 1) mn = fminf(mn, __shfl_xor(mn, off));
        if (lane == 0) Cn[i] = mn;  // row min == DP value; also softmax pivot
        float s = 0.0f;
#pragma unroll
        for (int c = 0; c < 32; ++c) {
            const int j = j0 + c * 64;
            float p = 0.0f;
            if (j < jmax) p = __expf(mn - mv[c]);
            mv[c] = p;
            s += p;
        }
#pragma unroll
        for (int off = 32; off; off >>= 1) s += __shfl_xor(s, off);
        const float inv = 1.0f / s;
#pragma unroll
        for (int c = 0; c < 32; ++c) {
            const int j = j0 + c * 64;
            if (j < jmax) atomicAdd(&acc[j], mv[c] * inv);
        }
    }
    __syncthreads();
    float* ts = tsum + b * NTOK;
    for (int j = t; j < NTOK; j += 256) {
        const float v = acc[j];
        if (v != 0.0f) atomicAdd(&ts[j], v);
    }
}

// out[b][j] = (tsum + N*[j==N-1]) / tcnt, tcnt analytic.
__global__ void finalize_kernel(const float* __restrict__ tsum, float* __restrict__ out)
{
    const int b = blockIdx.y;
    const int j = blockIdx.x * 256 + threadIdx.x;
    if (j >= NTOK) return;
    float ts = tsum[b * NTOK + j];
    int steps = NTOK - 1 - j;
    if (steps > KSEG - 1) steps = KSEG - 1;
    float tc = (float)(j + 1) * (float)steps;
    if (j == NTOK - 1) { ts += (float)NTOK; tc += (float)NTOK; }
    out[b * NTOK + j] = ts / tc;
}

extern "C" void kernel_launch(void* const* d_in, const int* in_sizes, int n_in,
                              void* d_out, int out_size, void* d_ws, size_t ws_size,
                              hipStream_t stream)
{
    const float* x  = (const float*)d_in[0];
    const float* W0 = (const float*)d_in[1];
    const float* b0 = (const float*)d_in[2];
    const float* W1 = (const float*)d_in[3];
    const float* b1 = (const float*)d_in[4];
    float* out = (float*)d_out;

    char* ws = (char*)d_ws;
    size_t off = 0;
    auto alloc = [&](size_t bytes) -> void* {
        void* p = (void*)(ws + off);
        off += (bytes + 255) & ~(size_t)255;
        return p;
    };
    // ~113.5 MB total scratch
    double* Sp   = (double*)alloc((size_t)BATCH * ST2 * sizeof(double));          // 67.2 MB
    float*  Dm   = (float*) alloc((size_t)BATCH * NTOK * NTOK * sizeof(float));   // 33.6 MB (D, reused as Bsum)
    float*  h    = (float*) alloc((size_t)BATCH * NTOK * HDIM * sizeof(float));   // 8.4 MB
    float*  e    = (float*) alloc((size_t)BATCH * NTOK * EDIM * sizeof(float));   // 4.2 MB
    float*  dvec = (float*) alloc((size_t)BATCH * NTOK * sizeof(float));
    double* dg   = (double*)alloc((size_t)BATCH * NP1 * sizeof(double));
    double* aux  = (double*)alloc((size_t)BATCH * 8 * NP1 * sizeof(double));
    float*  CA   = (float*) alloc((size_t)BATCH * NTOK * sizeof(float));
    float*  CB   = (float*) alloc((size_t)BATCH * NTOK * sizeof(float));
    float*  tsum = (float*) alloc((size_t)BATCH * NTOK * sizeof(float));
    (void)ws_size; (void)in_sizes; (void)n_in; (void)out_size;

    hipMemsetAsync(tsum, 0, (size_t)BATCH * NTOK * sizeof(float), stream);

    // h = relu(x @ W0^T + b0)   [4096 x 512]
    gemm_nt<0><<<dim3(HDIM / 64, (BATCH * NTOK) / 64, 1), 256, 0, stream>>>(
        x, FDIM, 0, W0, FDIM, 0, b0, h, HDIM, 0, FDIM, nullptr);
    // e = h @ W1^T + b1         [4096 x 256]
    gemm_nt<1><<<dim3(EDIM / 64, (BATCH * NTOK) / 64, 1), 256, 0, stream>>>(
        h, HDIM, 0, W1, HDIM, 0, b1, e, EDIM, 0, HDIM, nullptr);
    // d[i] = ||e_i||^2
    rownorm_kernel<<<dim3((BATCH * NTOK) / 4), 256, 0, stream>>>(e, dvec);
    // D = 0.5*(1 - (e e^T)/sqrt(clip(d_i d_j,1e-8)))  per batch
    gemm_nt<2><<<dim3(NTOK / 64, NTOK / 64, BATCH), 256, 0, stream>>>(
        e, EDIM, (size_t)NTOK * EDIM, e, EDIM, (size_t)NTOK * EDIM, nullptr,
        Dm, NTOK, (size_t)NTOK * NTOK, EDIM, dvec);
    // Summed-area table in f64
    sat_row_kernel<<<dim3(NTOK, BATCH), 256, 0, stream>>>(Dm, Sp);
    satc1<<<dim3((NP1 + 255) / 256, 8, BATCH), 256, 0, stream>>>(Sp, aux);
    satc2<<<dim3((NP1 + 255) / 256, BATCH), 256, 0, stream>>>(aux);
    satc3<<<dim3((NP1 + 255) / 256, 8, BATCH), 256, 0, stream>>>(Sp, aux);
    diag_kernel<<<dim3((NP1 + 255) / 256, BATCH), 256, 0, stream>>>(Sp, dg);
    // Bsum (overwrites D buffer) + C0
    bsum_kernel<<<dim3(NTOK, BATCH), 256, 0, stream>>>(Sp, dg, Dm, CA);
    // 29 sequential DP steps
    float* cp = CA; float* cn = CB;
    for (int kk = 1; kk < KSEG; ++kk) {
        dp_step_kernel<<<dim3(128, BATCH), 256, 0, stream>>>(Dm, cp, cn, tsum, kk);
        float* tmp = cp; cp = cn; cn = tmp;
    }
    finalize_kernel<<<dim3(NTOK / 256, BATCH), 256, 0, stream>>>(tsum, out);
}